// Round 1
// baseline (455.696 us; speedup 1.0000x reference)
//
#include <hip/hip_runtime.h>

typedef __attribute__((ext_vector_type(8))) __bf16 bf16x8;
typedef __attribute__((ext_vector_type(4))) float f32x4;
typedef __attribute__((ext_vector_type(4))) unsigned int u32x4;
typedef __attribute__((ext_vector_type(4))) unsigned short u16x4;
typedef unsigned short u16;

static __device__ __forceinline__ u16 f2b(float f) {
    unsigned u = __builtin_bit_cast(unsigned, f);
    u = (u + 0x7FFFu + ((u >> 16) & 1u)) >> 16;
    return (u16)u;
}

// ---------------- weight transpose+convert: src[K][N] f32 -> dst[N][K] bf16 ----
__global__ __launch_bounds__(256) void prep_w(
    const float* __restrict__ Wq, const float* __restrict__ Wk,
    const float* __restrict__ Wv, const float* __restrict__ Wo,
    const float* __restrict__ W1, const float* __restrict__ W2,
    u16* __restrict__ WqkvT, u16* __restrict__ WoT,
    u16* __restrict__ W1T, u16* __restrict__ W2T)
{
    const int z = blockIdx.z;
    const float* src; u16* dst; int K, N;
    if (z == 0)      { src = Wq; dst = WqkvT;             K = 512;  N = 512;  }
    else if (z == 1) { src = Wk; dst = WqkvT + 512*512;   K = 512;  N = 512;  }
    else if (z == 2) { src = Wv; dst = WqkvT + 1024*512;  K = 512;  N = 512;  }
    else if (z == 3) { src = Wo; dst = WoT;               K = 512;  N = 512;  }
    else if (z == 4) { src = W1; dst = W1T;               K = 512;  N = 2048; }
    else             { src = W2; dst = W2T;               K = 2048; N = 512;  }
    const int nt = blockIdx.x * 32, kt = blockIdx.y * 32;
    if (nt >= N || kt >= K) return;
    __shared__ float tile[32][33];
    const int tx = threadIdx.x & 31, ty = threadIdx.x >> 5;
    #pragma unroll
    for (int i = 0; i < 4; ++i)
        tile[ty + i*8][tx] = src[(size_t)(kt + ty + i*8) * N + nt + tx];
    __syncthreads();
    #pragma unroll
    for (int i = 0; i < 4; ++i)
        dst[(size_t)(nt + ty + i*8) * K + kt + tx] = f2b(tile[tx][ty + i*8]);
}

// ---------------- LayerNorm rows: [8192][512] f32 -> bf16 ----------------------
__global__ __launch_bounds__(256) void ln_rows(
    const float* __restrict__ x, const float* __restrict__ g,
    const float* __restrict__ b, u16* __restrict__ out)
{
    const int row = blockIdx.x * 4 + (threadIdx.x >> 6);
    const int lane = threadIdx.x & 63;
    const float* xr = x + (size_t)row * 512;
    f32x4 v0 = *(const f32x4*)(xr + lane * 4);
    f32x4 v1 = *(const f32x4*)(xr + 256 + lane * 4);
    float s = v0[0]+v0[1]+v0[2]+v0[3]+v1[0]+v1[1]+v1[2]+v1[3];
    #pragma unroll
    for (int o = 1; o < 64; o <<= 1) s += __shfl_xor(s, o);
    const float mu = s * (1.0f / 512.0f);
    float s2 = 0.f;
    #pragma unroll
    for (int i = 0; i < 4; ++i) { float d0 = v0[i]-mu, d1 = v1[i]-mu; s2 += d0*d0 + d1*d1; }
    #pragma unroll
    for (int o = 1; o < 64; o <<= 1) s2 += __shfl_xor(s2, o);
    const float inv = rsqrtf(s2 * (1.0f/512.0f) + 1e-5f);
    f32x4 g0 = *(const f32x4*)(g + lane*4), g1 = *(const f32x4*)(g + 256 + lane*4);
    f32x4 b0 = *(const f32x4*)(b + lane*4), b1 = *(const f32x4*)(b + 256 + lane*4);
    u16x4 p0, p1;
    #pragma unroll
    for (int i = 0; i < 4; ++i) {
        p0[i] = f2b((v0[i]-mu)*inv*g0[i] + b0[i]);
        p1[i] = f2b((v1[i]-mu)*inv*g1[i] + b1[i]);
    }
    u16* orow = out + (size_t)row * 512;
    *(u16x4*)(orow + lane*4)       = p0;
    *(u16x4*)(orow + 256 + lane*4) = p1;
}

// ---------------- GEMM: C[M][N] = A[M][K](bf16) * BT[N][K](bf16)^T + epilogue --
// FLAGS: 1=bias, 2=residual(f32), 4=relu, 8=store f32 (else bf16)
template<int FLAGS>
__global__ __launch_bounds__(256) void gemm_bt(
    const u16* __restrict__ A, const u16* __restrict__ BT,
    const int N, const int K,
    const float* __restrict__ bias, const float* __restrict__ res,
    void* __restrict__ outv)
{
    __shared__ __attribute__((aligned(16))) u16 As[128*32];
    __shared__ __attribute__((aligned(16))) u16 Bs[128*32];
    const int tid = threadIdx.x, lane = tid & 63, w = tid >> 6;
    const int wr = w >> 1, wc = w & 1;
    const int m0 = blockIdx.y << 7, n0 = blockIdx.x << 7;
    const int g = lane >> 4, c = lane & 15;
    const f32x4 fz = {0.f, 0.f, 0.f, 0.f};

    f32x4 acc[4][4];
    #pragma unroll
    for (int m = 0; m < 4; ++m)
      #pragma unroll
      for (int n = 0; n < 4; ++n) acc[m][n] = fz;

    // staging: thread -> 2 chunks (rows tid>>2 and 64+tid>>2, 16B chunk tid&3)
    const int srow = tid >> 2, sch = tid & 3;
    const int sOff0 = srow*32 + (((sch*16) ^ ((srow&3)<<4)) >> 1);
    const int sOff1 = sOff0 + 64*32;
    const u16* Ag = A  + (size_t)(m0 + srow)*K + sch*8;
    const u16* Bg = BT + (size_t)(n0 + srow)*K + sch*8;
    const size_t rstep = (size_t)64 * K;

    const int nkt = K >> 5;
    for (int kt = 0; kt < nkt; ++kt) {
        const int k0 = kt << 5;
        u32x4 a0 = *(const u32x4*)(Ag + k0);
        u32x4 a1 = *(const u32x4*)(Ag + rstep + k0);
        u32x4 b0 = *(const u32x4*)(Bg + k0);
        u32x4 b1 = *(const u32x4*)(Bg + rstep + k0);
        *(u32x4*)(As + sOff0) = a0;
        *(u32x4*)(As + sOff1) = a1;
        *(u32x4*)(Bs + sOff0) = b0;
        *(u32x4*)(Bs + sOff1) = b1;
        __syncthreads();
        bf16x8 af[4], bfr[4];
        #pragma unroll
        for (int m = 0; m < 4; ++m) {
            const int row = wr*64 + m*16 + c;
            af[m] = *(const bf16x8*)(As + row*32 + (((g*16) ^ ((row&3)<<4)) >> 1));
        }
        #pragma unroll
        for (int n = 0; n < 4; ++n) {
            const int row = wc*64 + n*16 + c;
            bfr[n] = *(const bf16x8*)(Bs + row*32 + (((g*16) ^ ((row&3)<<4)) >> 1));
        }
        #pragma unroll
        for (int m = 0; m < 4; ++m)
          #pragma unroll
          for (int n = 0; n < 4; ++n)
            acc[m][n] = __builtin_amdgcn_mfma_f32_16x16x32_bf16(af[m], bfr[n], acc[m][n], 0, 0, 0);
        __syncthreads();
    }

    #pragma unroll
    for (int m = 0; m < 4; ++m) {
        const int row = m0 + wr*64 + m*16 + 4*g;
        #pragma unroll
        for (int n = 0; n < 4; ++n) {
            const int col = n0 + wc*64 + n*16 + c;
            const float bv = (FLAGS & 1) ? bias[col] : 0.0f;
            #pragma unroll
            for (int r = 0; r < 4; ++r) {
                float v = acc[m][n][r] + bv;
                if (FLAGS & 2) v += res[(size_t)(row + r)*N + col];
                if (FLAGS & 4) v = fmaxf(v, 0.0f);
                if (FLAGS & 8) ((float*)outv)[(size_t)(row + r)*N + col] = v;
                else           ((u16*)outv)[(size_t)(row + r)*N + col] = f2b(v);
            }
        }
    }
}

// ---------------- V transpose: qkv cols [1024..1536) -> vT[B*H*64][4096] ------
__global__ __launch_bounds__(256) void transpose_v(
    const u16* __restrict__ qkv, u16* __restrict__ vT)
{
    const int b = blockIdx.z;
    const int t0 = blockIdx.x * 32, c0 = blockIdx.y * 32;
    __shared__ u16 tile[32][33];
    const int tx = threadIdx.x & 31, ty = threadIdx.x >> 5;
    #pragma unroll
    for (int i = 0; i < 4; ++i)
        tile[ty + i*8][tx] =
            qkv[(size_t)(b*4096 + t0 + ty + i*8)*1536 + 1024 + c0 + tx];
    __syncthreads();
    #pragma unroll
    for (int i = 0; i < 4; ++i)
        vT[(size_t)(b*512 + c0 + ty + i*8)*4096 + t0 + tx] = tile[tx][ty + i*8];
}

// ---------------- causal flash attention ---------------------------------------
// grid (T/64, B*H); 256 thr = 4 waves; wave w owns q rows [q0+16w, q0+16w+16)
__global__ __launch_bounds__(256) void attn_fwd(
    const u16* __restrict__ qkv, const u16* __restrict__ vT, u16* __restrict__ outp)
{
    const int bh = blockIdx.y, b = bh >> 3, h = bh & 7;
    const int q0 = blockIdx.x * 64;
    const int tid = threadIdx.x, lane = tid & 63, w = tid >> 6;
    const int g = lane >> 4, c = lane & 15;
    __shared__ __attribute__((aligned(16))) u16 Ks[32*64];
    __shared__ __attribute__((aligned(16))) u16 Vs[64*32];
    __shared__ __attribute__((aligned(16))) u16 Ps[4][16*40];

    const u16* qp  = qkv + (size_t)b*4096*1536 + h*64;
    const u16* kp  = qp + 512;
    const u16* vtp = vT + (size_t)bh*64*4096;

    const int qrow = q0 + w*16 + c;           // A-fragment row
    const bf16x8 qf0 = *(const bf16x8*)(qp + (size_t)qrow*1536 + g*8);
    const bf16x8 qf1 = *(const bf16x8*)(qp + (size_t)qrow*1536 + 32 + g*8);

    float mrow[4] = {-INFINITY, -INFINITY, -INFINITY, -INFINITY};
    float lrow[4] = {0.f, 0.f, 0.f, 0.f};
    const f32x4 fz = {0.f, 0.f, 0.f, 0.f};
    f32x4 oacc[4] = {fz, fz, fz, fz};

    const int qmaxw = q0 + w*16 + 15;
    const int qbase = q0 + w*16 + 4*g;        // + r = this lane's S/O row
    const int ntiles = (q0 >> 5) + 2;
    const float scale = 0.04419417382415922f; // 512^-0.5

    const int krow = tid >> 3, kch = tid & 7;
    const int vrow = tid >> 2, vch = tid & 3;
    const int ksoff = krow*64 + (((kch*16) ^ ((krow&7)<<4)) >> 1);
    const int vsoff = vrow*32 + (((vch*16) ^ ((vrow&3)<<4)) >> 1);

    for (int t = 0; t < ntiles; ++t) {
        const int kv0 = t << 5;
        u32x4 kd = *(const u32x4*)(kp + (size_t)(kv0 + krow)*1536 + kch*8);
        u32x4 vd = *(const u32x4*)(vtp + (size_t)vrow*4096 + kv0 + vch*8);
        *(u32x4*)(Ks + ksoff) = kd;
        *(u32x4*)(Vs + vsoff) = vd;
        __syncthreads();
        if (kv0 <= qmaxw) {
            f32x4 s0 = fz, s1 = fz;
            {
                const int r0 = c, r1 = 16 + c;
                bf16x8 kb;
                kb = *(const bf16x8*)(Ks + r0*64 + ((((0  + g*16)) ^ ((r0&7)<<4)) >> 1));
                s0 = __builtin_amdgcn_mfma_f32_16x16x32_bf16(qf0, kb, s0, 0, 0, 0);
                kb = *(const bf16x8*)(Ks + r0*64 + ((((64 + g*16)) ^ ((r0&7)<<4)) >> 1));
                s0 = __builtin_amdgcn_mfma_f32_16x16x32_bf16(qf1, kb, s0, 0, 0, 0);
                kb = *(const bf16x8*)(Ks + r1*64 + ((((0  + g*16)) ^ ((r1&7)<<4)) >> 1));
                s1 = __builtin_amdgcn_mfma_f32_16x16x32_bf16(qf0, kb, s1, 0, 0, 0);
                kb = *(const bf16x8*)(Ks + r1*64 + ((((64 + g*16)) ^ ((r1&7)<<4)) >> 1));
                s1 = __builtin_amdgcn_mfma_f32_16x16x32_bf16(qf1, kb, s1, 0, 0, 0);
            }
            #pragma unroll
            for (int r = 0; r < 4; ++r) {
                const int qi = qbase + r;
                float v0 = s0[r]*scale, v1 = s1[r]*scale;
                if (kv0 + c > qi)      v0 = -1e30f;
                if (kv0 + 16 + c > qi) v1 = -1e30f;
                float mx = fmaxf(v0, v1);
                mx = fmaxf(mx, __shfl_xor(mx, 1));
                mx = fmaxf(mx, __shfl_xor(mx, 2));
                mx = fmaxf(mx, __shfl_xor(mx, 4));
                mx = fmaxf(mx, __shfl_xor(mx, 8));
                const float mn = fmaxf(mrow[r], mx);
                const float al = __expf(mrow[r] - mn);
                const float p0 = __expf(v0 - mn), p1 = __expf(v1 - mn);
                float rs = p0 + p1;
                rs += __shfl_xor(rs, 1);
                rs += __shfl_xor(rs, 2);
                rs += __shfl_xor(rs, 4);
                rs += __shfl_xor(rs, 8);
                lrow[r] = lrow[r]*al + rs;
                mrow[r] = mn;
                oacc[0][r] *= al; oacc[1][r] *= al; oacc[2][r] *= al; oacc[3][r] *= al;
                Ps[w][(4*g + r)*40 + c]      = f2b(p0);
                Ps[w][(4*g + r)*40 + 16 + c] = f2b(p1);
            }
            const bf16x8 pa = *(const bf16x8*)(&Ps[w][c*40 + g*8]);
            #pragma unroll
            for (int dt = 0; dt < 4; ++dt) {
                const int vr = dt*16 + c;
                const bf16x8 vb = *(const bf16x8*)(Vs + vr*32 + (((g*16) ^ ((vr&3)<<4)) >> 1));
                oacc[dt] = __builtin_amdgcn_mfma_f32_16x16x32_bf16(pa, vb, oacc[dt], 0, 0, 0);
            }
        }
        __syncthreads();
    }

    u16* orow = outp + (size_t)(b*4096 + qbase)*512 + h*64 + c;
    #pragma unroll
    for (int r = 0; r < 4; ++r) {
        const float inv = 1.0f / lrow[r];
        #pragma unroll
        for (int dt = 0; dt < 4; ++dt)
            orow[(size_t)r*512 + dt*16] = f2b(oacc[dt][r] * inv);
    }
}

// -------------------------------------------------------------------------------
extern "C" void kernel_launch(void* const* d_in, const int* in_sizes, int n_in,
                              void* d_out, int out_size, void* d_ws, size_t ws_size,
                              hipStream_t stream)
{
    (void)in_sizes; (void)n_in; (void)out_size; (void)ws_size;
    const float* x   = (const float*)d_in[0];
    const float* Wq  = (const float*)d_in[1];
    const float* Wk  = (const float*)d_in[2];
    const float* Wv  = (const float*)d_in[3];
    const float* Wo  = (const float*)d_in[4];
    const float* bo  = (const float*)d_in[5];
    const float* W1  = (const float*)d_in[6];
    const float* b1  = (const float*)d_in[7];
    const float* W2  = (const float*)d_in[8];
    const float* b2  = (const float*)d_in[9];
    const float* g1  = (const float*)d_in[10];
    const float* be1 = (const float*)d_in[11];
    const float* g2  = (const float*)d_in[12];
    const float* be2 = (const float*)d_in[13];

    char* ws = (char*)d_ws;
    u16*   WqkvT = (u16*)(ws + 0);
    u16*   WoT   = (u16*)(ws + 1572864);
    u16*   W1T   = (u16*)(ws + 2097152);
    u16*   W2T   = (u16*)(ws + 4194304);
    u16*   H     = (u16*)(ws + 6291456);    // ln1 out, reused for ln2 out
    float* X2    = (float*)(ws + 14680064); // post-attention residual (f32)
    u16*   QKV   = (u16*)(ws + 31457280);   // [8192][1536]
    u16*   VT    = (u16*)(ws + 56623104);   // [1024][4096]
    u16*   ATT   = (u16*)(ws + 65011712);   // [8192][512]
    u16*   F1    = (u16*)(ws + 31457280);   // [8192][2048], reuses QKV+VT

    prep_w<<<dim3(64, 64, 6), 256, 0, stream>>>(Wq, Wk, Wv, Wo, W1, W2,
                                                WqkvT, WoT, W1T, W2T);
    ln_rows<<<2048, 256, 0, stream>>>(x, g1, be1, H);
    gemm_bt<0><<<dim3(12, 64), 256, 0, stream>>>(H, WqkvT, 1536, 512,
                                                 nullptr, nullptr, QKV);
    transpose_v<<<dim3(128, 16, 2), 256, 0, stream>>>(QKV, VT);
    attn_fwd<<<dim3(64, 16), 256, 0, stream>>>(QKV, VT, ATT);
    gemm_bt<11><<<dim3(4, 64), 256, 0, stream>>>(ATT, WoT, 512, 512,
                                                 bo, x, X2);
    ln_rows<<<2048, 256, 0, stream>>>(X2, g2, be2, H);
    gemm_bt<5><<<dim3(16, 64), 256, 0, stream>>>(H, W1T, 2048, 512,
                                                 b1, nullptr, F1);
    gemm_bt<11><<<dim3(4, 64), 256, 0, stream>>>(F1, W2T, 512, 2048,
                                                 b2, X2, (float*)d_out);
}